// Round 1
// baseline (1086.573 us; speedup 1.0000x reference)
//
#include <hip/hip_runtime.h>

// ---------------- problem constants (fixed by setup_inputs) ----------------
#define BB 4
#define HH 512
#define WW 512
#define NPT 2000          // N points kept per image
#define MPT 2500          // M points generated per image
#define CCH 128           // channels
#define FH 128            // feature map h = H/4
#define FW 128
#define FHW (FH*FW)
#define BNP (BB*NPT)      // 8000
#define NPOSC 29
#define NNEGC 80
#define NCOL (1 + NNEGC + BNP)   // 8081 columns in scores/gt

// offsets exactly in the reference enumeration order (j outer, i inner)
__constant__ int c_pos_dy[NPOSC] = {
  0,
  -2,-1,0,1,2,
  -2,-1,0,1,2,
  -3,-2,-1,0,1,2,3,
  -2,-1,0,1,2,
  -2,-1,0,1,2,
  0};
__constant__ int c_pos_dx[NPOSC] = {
  -3,
  -2,-2,-2,-2,-2,
  -1,-1,-1,-1,-1,
  0,0,0,0,0,0,0,
  1,1,1,1,1,
  2,2,2,2,2,
  3};
__constant__ int c_neg_dy[NNEGC] = {
  0,
  -3,-2,-1,0,1,2,3,
  -4,-3,-2,-1,0,1,2,3,4,
  -5,-4,-3,3,4,5,
  -6,-5,-4,4,5,6,
  -6,-5,5,6,
  -6,-5,5,6,
  -7,-6,-5,5,6,7,
  -6,-5,5,6,
  -6,-5,5,6,
  -6,-5,-4,4,5,6,
  -5,-4,-3,3,4,5,
  -4,-3,-2,-1,0,1,2,3,4,
  -3,-2,-1,0,1,2,3,
  0};
__constant__ int c_neg_dx[NNEGC] = {
  -7,
  -6,-6,-6,-6,-6,-6,-6,
  -5,-5,-5,-5,-5,-5,-5,-5,-5,
  -4,-4,-4,-4,-4,-4,
  -3,-3,-3,-3,-3,-3,
  -2,-2,-2,-2,
  -1,-1,-1,-1,
  0,0,0,0,0,0,
  1,1,1,1,
  2,2,2,2,
  3,3,3,3,3,3,
  4,4,4,4,4,4,
  5,5,5,5,5,5,5,5,5,
  6,6,6,6,6,6,6,
  7};

// ---------------- device helpers ----------------
// bilinear sample of 2 channels (c = 2*lane, 2*lane+1) from channel-contiguous
// feature map fb[FH][FW][CCH]; fy/fx are feature-scale coords (already /4),
// clipped to [0, FH-1] exactly like the reference's bilinear().
__device__ __forceinline__ float2 sample2(const float* __restrict__ fb,
                                          float fy, float fx, int lane) {
  float y = fminf(fmaxf(fy, 0.f), (float)(FH - 1));
  float x = fminf(fmaxf(fx, 0.f), (float)(FW - 1));
  float y0 = floorf(y), x0 = floorf(x);
  int iy0 = (int)y0, ix0 = (int)x0;
  int iy1 = min(iy0 + 1, FH - 1), ix1 = min(ix0 + 1, FW - 1);
  float wy = y - y0, wx = x - x0;
  float w00 = (1.f - wy) * (1.f - wx), w01 = (1.f - wy) * wx;
  float w10 = wy * (1.f - wx),         w11 = wy * wx;
  int c = 2 * lane;
  float2 a00 = *(const float2*)(fb + ((size_t)iy0 * FW + ix0) * CCH + c);
  float2 a01 = *(const float2*)(fb + ((size_t)iy0 * FW + ix1) * CCH + c);
  float2 a10 = *(const float2*)(fb + ((size_t)iy1 * FW + ix0) * CCH + c);
  float2 a11 = *(const float2*)(fb + ((size_t)iy1 * FW + ix1) * CCH + c);
  float2 r;
  r.x = w00 * a00.x + w01 * a01.x + w10 * a10.x + w11 * a11.x;
  r.y = w00 * a00.y + w01 * a01.y + w10 * a10.y + w11 * a11.y;
  return r;
}

// single-channel bilinear on conf map cb[FH][FW]; py/px are IMAGE-scale coords
__device__ __forceinline__ float conf_sample(const float* __restrict__ cb,
                                             float py, float px) {
  float y = fminf(fmaxf(py * 0.25f, 0.f), (float)(FH - 1));
  float x = fminf(fmaxf(px * 0.25f, 0.f), (float)(FW - 1));
  float y0 = floorf(y), x0 = floorf(x);
  int iy0 = (int)y0, ix0 = (int)x0;
  int iy1 = min(iy0 + 1, FH - 1), ix1 = min(ix0 + 1, FW - 1);
  float wy = y - y0, wx = x - x0;
  return (1.f - wy) * (1.f - wx) * cb[iy0 * FW + ix0]
       + (1.f - wy) * wx         * cb[iy0 * FW + ix1]
       + wy * (1.f - wx)         * cb[iy1 * FW + ix0]
       + wy * wx                 * cb[iy1 * FW + ix1];
}

__device__ __forceinline__ float wave_sum(float v) {
#pragma unroll
  for (int o = 32; o > 0; o >>= 1) v += __shfl_xor(v, o, 64);
  return v;
}

// score of one candidate: sample fc (2 ch/lane), wave-reduce (sumsq, dot),
// score = dot / max(||fc||, 1e-12). cyi/cxi are integer image coords.
__device__ __forceinline__ float cand_score(const float* __restrict__ fb,
                                            int cyi, int cxi,
                                            float a0, float a1, int lane) {
  float cy = fminf(fmaxf((float)cyi, 0.f), (float)(HH - 1));
  float cx = fminf(fmaxf((float)cxi, 0.f), (float)(WW - 1));
  float2 v = sample2(fb, cy * 0.25f, cx * 0.25f, lane);
  float dot = a0 * v.x + a1 * v.y;
  float ss  = v.x * v.x + v.y * v.y;
#pragma unroll
  for (int o = 32; o > 0; o >>= 1) {
    dot += __shfl_xor(dot, o, 64);
    ss  += __shfl_xor(ss,  o, 64);
  }
  return dot / fmaxf(sqrtf(ss), 1e-12f);
}

// ---------------- K1: transpose feats [C][h][w] -> [h][w][C] ----------------
__global__ __launch_bounds__(256) void k_transpose(const float* __restrict__ feat0,
                                                   const float* __restrict__ feat1,
                                                   float* __restrict__ ft0,
                                                   float* __restrict__ ft1) {
  __shared__ float tile[32][33];
  int z = blockIdx.z;
  const float* src = (z < BB) ? feat0 + (size_t)z * CCH * FHW
                              : feat1 + (size_t)(z - BB) * CCH * FHW;
  float* dst = (z < BB) ? ft0 + (size_t)z * CCH * FHW
                        : ft1 + (size_t)(z - BB) * CCH * FHW;
  int p0 = blockIdx.x * 32;   // position tile (p = y*FW + x)
  int c0 = blockIdx.y * 32;   // channel tile
  int tx = threadIdx.x & 31, ty = threadIdx.x >> 5;  // ty 0..7
#pragma unroll
  for (int jj = 0; jj < 32; jj += 8)
    tile[ty + jj][tx] = src[(size_t)(c0 + ty + jj) * FHW + p0 + tx];
  __syncthreads();
#pragma unroll
  for (int jj = 0; jj < 32; jj += 8)
    dst[(size_t)(p0 + ty + jj) * CCH + c0 + tx] = tile[tx][ty + jj];
}

// ---------------- K2: per-point prep (vf0, vf0_t, dist_t, mask) -------------
__global__ __launch_bounds__(256) void k_prep(const float* __restrict__ ft0,
                                              const float* __restrict__ ft1,
                                              const int* __restrict__ pos0,
                                              const int* __restrict__ pos1,
                                              float* __restrict__ vf0,
                                              float* __restrict__ vf0_t,
                                              float* __restrict__ dist_t,
                                              float* __restrict__ mask_out) {
  __shared__ float stg[4][CCH + 1];
  int wv = threadIdx.x >> 6, lane = threadIdx.x & 63;
  int n0 = blockIdx.x * 4;
  int n = n0 + wv;
  int b = n / NPT, r = n % NPT;

  // ---- vf0 = l2norm(bilinear(pos0[:N]/4, feat0)) ----
  {
    const float* fb = ft0 + (size_t)b * FHW * CCH;
    float py = (float)pos0[(b * MPT + r) * 2 + 0];
    float px = (float)pos0[(b * MPT + r) * 2 + 1];
    float2 v = sample2(fb, py * 0.25f, px * 0.25f, lane);
    float ss = wave_sum(v.x * v.x + v.y * v.y);
    float inv = 1.f / fmaxf(sqrtf(ss), 1e-12f);
    v.x *= inv; v.y *= inv;
    *(float2*)(vf0 + (size_t)n * CCH + 2 * lane) = v;
    stg[wv][2 * lane] = v.x; stg[wv][2 * lane + 1] = v.y;
  }
  __syncthreads();
  {
    int k = threadIdx.x & 127, g = threadIdx.x >> 7;  // g 0..1
    float2 o; o.x = stg[g * 2][k]; o.y = stg[g * 2 + 1][k];
    *(float2*)(vf0_t + (size_t)k * BNP + n0 + g * 2) = o;
  }
  __syncthreads();

  // ---- dist = l2norm(bilinear(pos1[M-N:]/4, feat1)) ----
  {
    const float* fb = ft1 + (size_t)b * FHW * CCH;
    float py = (float)pos1[(b * MPT + (MPT - NPT) + r) * 2 + 0];
    float px = (float)pos1[(b * MPT + (MPT - NPT) + r) * 2 + 1];
    float2 v = sample2(fb, py * 0.25f, px * 0.25f, lane);
    float ss = wave_sum(v.x * v.x + v.y * v.y);
    float inv = 1.f / fmaxf(sqrtf(ss), 1e-12f);
    v.x *= inv; v.y *= inv;
    stg[wv][2 * lane] = v.x; stg[wv][2 * lane + 1] = v.y;
  }
  __syncthreads();
  {
    int k = threadIdx.x & 127, g = threadIdx.x >> 7;
    float2 o; o.x = stg[g * 2][k]; o.y = stg[g * 2 + 1][k];
    *(float2*)(dist_t + (size_t)k * BNP + n0 + g * 2) = o;
  }

  // ---- mask (vp1 in-bounds; always true for these inputs but compute) ----
  if (lane == 0) {
    int my = pos1[(b * MPT + r) * 2 + 0];
    int mx = pos1[(b * MPT + r) * 2 + 1];
    mask_out[n] = (mx >= 0 && mx < WW && my >= 0 && my < HH) ? 1.f : 0.f;
  }
}

// ---------------- K3: candidates (pscore/argmax, nscores, qconf, gt head) ---
__global__ __launch_bounds__(256) void k_cand(const float* __restrict__ ft1,
                                              const float* __restrict__ conf0,
                                              const float* __restrict__ conf1,
                                              const int* __restrict__ pos0,
                                              const int* __restrict__ pos1,
                                              const float* __restrict__ vf0,
                                              float* __restrict__ scores,
                                              float* __restrict__ gt,
                                              float* __restrict__ qconf_out) {
  int n = blockIdx.x;
  int b = n / NPT, r = n % NPT;
  int wv = threadIdx.x >> 6, lane = threadIdx.x & 63;
  const float* fb1 = ft1 + (size_t)b * FHW * CCH;
  int py = pos1[(b * MPT + r) * 2 + 0];
  int px = pos1[(b * MPT + r) * 2 + 1];
  float2 a = *(const float2*)(vf0 + (size_t)n * CCH + 2 * lane);

  __shared__ float s_best[4];
  __shared__ int   s_idx[4];

  // positive candidates: wave wv takes p = wv, wv+4, ...
  float best = -1e30f; int bidx = 0;
  for (int p = wv; p < NPOSC; p += 4) {
    float sc = cand_score(fb1, py + c_pos_dy[p], px + c_pos_dx[p], a.x, a.y, lane);
    if (sc > best) { best = sc; bidx = p; }   // strict > keeps first occurrence
  }
  if (lane == 0) { s_best[wv] = best; s_idx[wv] = bidx; }
  __syncthreads();
  if (threadIdx.x == 0) {
    float bb = s_best[0]; int bi = s_idx[0];
#pragma unroll
    for (int w2 = 1; w2 < 4; ++w2) {
      float v = s_best[w2]; int i2 = s_idx[w2];
      if (v > bb || (v == bb && i2 < bi)) { bb = v; bi = i2; }  // first-max tie
    }
    scores[(size_t)n * NCOL] = bb;
    // qconf = (conf0@vp0 + conf1@sel)/2
    float q0 = conf_sample(conf0 + (size_t)b * FHW,
                           (float)pos0[(b * MPT + r) * 2 + 0],
                           (float)pos0[(b * MPT + r) * 2 + 1]);
    float sy = fminf(fmaxf((float)(py + c_pos_dy[bi]), 0.f), (float)(HH - 1));
    float sx = fminf(fmaxf((float)(px + c_pos_dx[bi]), 0.f), (float)(WW - 1));
    float q1 = conf_sample(conf1 + (size_t)b * FHW, sy, sx);
    qconf_out[n] = 0.5f * (q0 + q1);
  }
  // gt columns 0..80 (col 0 = 1, rest 0); cols 81+ are zeroed by the GEMM
  if (threadIdx.x <= NNEGC)
    gt[(size_t)n * NCOL + threadIdx.x] = (threadIdx.x == 0) ? 1.f : 0.f;

  // negative candidates -> scores cols 1..80
  for (int p = wv; p < NNEGC; p += 4) {
    float sc = cand_score(fb1, py + c_neg_dy[p], px + c_neg_dx[p], a.x, a.y, lane);
    if (lane == 0) scores[(size_t)n * NCOL + 1 + p] = sc;
  }
}

// ---------------- K4: masked GEMM scores[:,81:] = vf0 @ dist.T, gt zeros ----
#define BMN 128
#define BK 32
__global__ __launch_bounds__(256) void k_gemm(const float* __restrict__ vf0_t,
                                              const float* __restrict__ dist_t,
                                              const int* __restrict__ pos1,
                                              float* __restrict__ scores,
                                              float* __restrict__ gt) {
  __shared__ float As[BK][BMN];   // [k][i]
  __shared__ float Bs[BK][BMN];   // [k][j]
  int i0 = blockIdx.x * BMN, j0 = blockIdx.y * BMN;
  int tx = threadIdx.x & 15, ty = threadIdx.x >> 4;

  float acc[8][8];
#pragma unroll
  for (int m = 0; m < 8; ++m)
#pragma unroll
    for (int q = 0; q < 8; ++q) acc[m][q] = 0.f;

  int i4 = (threadIdx.x & 31) * 4;
  int kr = threadIdx.x >> 5;  // 0..7
  for (int ks = 0; ks < CCH; ks += BK) {
#pragma unroll
    for (int kk = 0; kk < 4; ++kk) {
      int k = kr + kk * 8;
      {
        int gi = i0 + i4;
        const float* src = vf0_t + (size_t)(ks + k) * BNP + gi;
        float4 v;
        if (gi + 3 < BNP) v = *(const float4*)src;
        else {
          v.x = (gi     < BNP) ? src[0] : 0.f;
          v.y = (gi + 1 < BNP) ? src[1] : 0.f;
          v.z = (gi + 2 < BNP) ? src[2] : 0.f;
          v.w = (gi + 3 < BNP) ? src[3] : 0.f;
        }
        *(float4*)&As[k][i4] = v;
      }
      {
        int gj = j0 + i4;
        const float* src = dist_t + (size_t)(ks + k) * BNP + gj;
        float4 v;
        if (gj + 3 < BNP) v = *(const float4*)src;
        else {
          v.x = (gj     < BNP) ? src[0] : 0.f;
          v.y = (gj + 1 < BNP) ? src[1] : 0.f;
          v.z = (gj + 2 < BNP) ? src[2] : 0.f;
          v.w = (gj + 3 < BNP) ? src[3] : 0.f;
        }
        *(float4*)&Bs[k][i4] = v;
      }
    }
    __syncthreads();
#pragma unroll
    for (int k = 0; k < BK; ++k) {
      float av[8], bv[8];
      *(float4*)&av[0] = *(float4*)&As[k][ty * 4];
      *(float4*)&av[4] = *(float4*)&As[k][ty * 4 + 64];
      *(float4*)&bv[0] = *(float4*)&Bs[k][tx * 4];
      *(float4*)&bv[4] = *(float4*)&Bs[k][tx * 4 + 64];
#pragma unroll
      for (int m = 0; m < 8; ++m)
#pragma unroll
        for (int q = 0; q < 8; ++q) acc[m][q] += av[m] * bv[q];
    }
    __syncthreads();
  }

  // epilogue: distance mask + store scores, zero gt
  int iw[8], jw[8];
#pragma unroll
  for (int m = 0; m < 4; ++m) {
    iw[m]     = i0 + ty * 4 + m;
    iw[m + 4] = i0 + 64 + ty * 4 + m;
    jw[m]     = j0 + tx * 4 + m;
    jw[m + 4] = j0 + 64 + tx * 4 + m;
  }
  float p1y[8], p1x[8], p2y[8], p2x[8];
  int bi[8], bj[8];
#pragma unroll
  for (int m = 0; m < 8; ++m) {
    int i = min(iw[m], BNP - 1);
    int b1 = i / NPT, r1 = i - b1 * NPT;
    bi[m] = b1;
    p1y[m] = (float)pos1[(b1 * MPT + r1) * 2 + 0];
    p1x[m] = (float)pos1[(b1 * MPT + r1) * 2 + 1];
    int j = min(jw[m], BNP - 1);
    int b2 = j / NPT, r2 = j - b2 * NPT;
    bj[m] = b2;
    p2y[m] = (float)pos1[(b2 * MPT + (MPT - NPT) + r2) * 2 + 0];
    p2x[m] = (float)pos1[(b2 * MPT + (MPT - NPT) + r2) * 2 + 1];
  }
#pragma unroll
  for (int m = 0; m < 8; ++m) {
    if (iw[m] >= BNP) continue;
    size_t rowS = (size_t)iw[m] * NCOL + 1 + NNEGC;
#pragma unroll
    for (int q = 0; q < 8; ++q) {
      if (jw[q] >= BNP) continue;
      float dy = p2y[q] - p1y[m];
      float dx = p2x[q] - p1x[m];
      float d2 = dy * dy + dx * dx + ((bi[m] != bj[q]) ? 25.f : 0.f);
      float val = (d2 < 25.f) ? 0.f : acc[m][q];
      scores[rowS + jw[q]] = val;
      gt[rowS + jw[q]] = 0.f;
    }
  }
}

// ---------------- launch ----------------
extern "C" void kernel_launch(void* const* d_in, const int* in_sizes, int n_in,
                              void* d_out, int out_size, void* d_ws, size_t ws_size,
                              hipStream_t stream) {
  (void)in_sizes; (void)n_in; (void)out_size; (void)ws_size;
  const float* feat0 = (const float*)d_in[0];
  const float* feat1 = (const float*)d_in[1];
  const float* conf0 = (const float*)d_in[2];
  const float* conf1 = (const float*)d_in[3];
  const int*   pos0  = (const int*)d_in[4];
  const int*   pos1  = (const int*)d_in[5];

  float* ws = (float*)d_ws;
  float* ft0    = ws;                                   // 4*128*128*128
  float* ft1    = ft0 + (size_t)BB * CCH * FHW;         // same
  float* vf0    = ft1 + (size_t)BB * CCH * FHW;         // 8000*128 row-major
  float* vf0_t  = vf0 + (size_t)BNP * CCH;              // [128][8000]
  float* dist_t = vf0_t + (size_t)BNP * CCH;            // [128][8000]

  float* out    = (float*)d_out;
  float* scores = out;                                  // [8000][8081]
  float* gt     = out + (size_t)BNP * NCOL;             // [8000][8081]
  float* maskp  = gt + (size_t)BNP * NCOL;              // [8000]
  float* qconf  = maskp + BNP;                          // [8000]

  dim3 g1(FHW / 32, CCH / 32, 2 * BB);
  k_transpose<<<g1, dim3(256), 0, stream>>>(feat0, feat1, ft0, ft1);
  k_prep<<<dim3(BNP / 4), dim3(256), 0, stream>>>(ft0, ft1, pos0, pos1,
                                                  vf0, vf0_t, dist_t, maskp);
  k_cand<<<dim3(BNP), dim3(256), 0, stream>>>(ft1, conf0, conf1, pos0, pos1,
                                              vf0, scores, gt, qconf);
  dim3 g4((BNP + BMN - 1) / BMN, (BNP + BMN - 1) / BMN);
  k_gemm<<<g4, dim3(256), 0, stream>>>(vf0_t, dist_t, pos1, scores, gt);
}

// Round 2
// 822.313 us; speedup vs baseline: 1.3214x; 1.3214x over previous
//
#include <hip/hip_runtime.h>

typedef unsigned short ushort_t;
typedef __attribute__((ext_vector_type(8))) short bf16x8;
typedef __attribute__((ext_vector_type(4))) float f32x4;

// ---------------- problem constants (fixed by setup_inputs) ----------------
#define BB 4
#define HH 512
#define WW 512
#define NPT 2000          // N points kept per image
#define MPT 2500          // M points generated per image
#define CCH 128           // channels
#define FH 128            // feature map h = H/4
#define FW 128
#define FHW (FH*FW)
#define BNP (BB*NPT)      // 8000
#define NPOSC 29
#define NNEGC 80
#define NCOL (1 + NNEGC + BNP)   // 8081 columns in scores/gt

// offsets exactly in the reference enumeration order (j outer, i inner)
__constant__ int c_pos_dy[NPOSC] = {
  0,
  -2,-1,0,1,2,
  -2,-1,0,1,2,
  -3,-2,-1,0,1,2,3,
  -2,-1,0,1,2,
  -2,-1,0,1,2,
  0};
__constant__ int c_pos_dx[NPOSC] = {
  -3,
  -2,-2,-2,-2,-2,
  -1,-1,-1,-1,-1,
  0,0,0,0,0,0,0,
  1,1,1,1,1,
  2,2,2,2,2,
  3};
__constant__ int c_neg_dy[NNEGC] = {
  0,
  -3,-2,-1,0,1,2,3,
  -4,-3,-2,-1,0,1,2,3,4,
  -5,-4,-3,3,4,5,
  -6,-5,-4,4,5,6,
  -6,-5,5,6,
  -6,-5,5,6,
  -7,-6,-5,5,6,7,
  -6,-5,5,6,
  -6,-5,5,6,
  -6,-5,-4,4,5,6,
  -5,-4,-3,3,4,5,
  -4,-3,-2,-1,0,1,2,3,4,
  -3,-2,-1,0,1,2,3,
  0};
__constant__ int c_neg_dx[NNEGC] = {
  -7,
  -6,-6,-6,-6,-6,-6,-6,
  -5,-5,-5,-5,-5,-5,-5,-5,-5,
  -4,-4,-4,-4,-4,-4,
  -3,-3,-3,-3,-3,-3,
  -2,-2,-2,-2,
  -1,-1,-1,-1,
  0,0,0,0,0,0,
  1,1,1,1,
  2,2,2,2,
  3,3,3,3,3,3,
  4,4,4,4,4,4,
  5,5,5,5,5,5,5,5,5,
  6,6,6,6,6,6,6,
  7};

// ---------------- device helpers ----------------
__device__ __forceinline__ ushort_t f2bf(float f) {   // round-to-nearest-even
  unsigned u = __float_as_uint(f);
  unsigned r = (u + 0x7fffu + ((u >> 16) & 1u)) >> 16;
  return (ushort_t)r;
}

// bilinear sample of 2 channels (c = 2*lane, 2*lane+1) from channel-contiguous
// feature map fb[FH][FW][CCH]; fy/fx are feature-scale coords (already /4)
__device__ __forceinline__ float2 sample2(const float* __restrict__ fb,
                                          float fy, float fx, int lane) {
  float y = fminf(fmaxf(fy, 0.f), (float)(FH - 1));
  float x = fminf(fmaxf(fx, 0.f), (float)(FW - 1));
  float y0 = floorf(y), x0 = floorf(x);
  int iy0 = (int)y0, ix0 = (int)x0;
  int iy1 = min(iy0 + 1, FH - 1), ix1 = min(ix0 + 1, FW - 1);
  float wy = y - y0, wx = x - x0;
  float w00 = (1.f - wy) * (1.f - wx), w01 = (1.f - wy) * wx;
  float w10 = wy * (1.f - wx),         w11 = wy * wx;
  int c = 2 * lane;
  float2 a00 = *(const float2*)(fb + ((size_t)iy0 * FW + ix0) * CCH + c);
  float2 a01 = *(const float2*)(fb + ((size_t)iy0 * FW + ix1) * CCH + c);
  float2 a10 = *(const float2*)(fb + ((size_t)iy1 * FW + ix0) * CCH + c);
  float2 a11 = *(const float2*)(fb + ((size_t)iy1 * FW + ix1) * CCH + c);
  float2 r;
  r.x = w00 * a00.x + w01 * a01.x + w10 * a10.x + w11 * a11.x;
  r.y = w00 * a00.y + w01 * a01.y + w10 * a10.y + w11 * a11.y;
  return r;
}

// candidate sample at integer image coords (applies image clamp then /4)
__device__ __forceinline__ float2 sample_cand(const float* __restrict__ fb,
                                              int cyi, int cxi, int lane) {
  float cy = fminf(fmaxf((float)cyi, 0.f), (float)(HH - 1));
  float cx = fminf(fmaxf((float)cxi, 0.f), (float)(WW - 1));
  return sample2(fb, cy * 0.25f, cx * 0.25f, lane);
}

// single-channel bilinear on conf map cb[FH][FW]; py/px are IMAGE-scale coords
__device__ __forceinline__ float conf_sample(const float* __restrict__ cb,
                                             float py, float px) {
  float y = fminf(fmaxf(py * 0.25f, 0.f), (float)(FH - 1));
  float x = fminf(fmaxf(px * 0.25f, 0.f), (float)(FW - 1));
  float y0 = floorf(y), x0 = floorf(x);
  int iy0 = (int)y0, ix0 = (int)x0;
  int iy1 = min(iy0 + 1, FH - 1), ix1 = min(ix0 + 1, FW - 1);
  float wy = y - y0, wx = x - x0;
  return (1.f - wy) * (1.f - wx) * cb[iy0 * FW + ix0]
       + (1.f - wy) * wx         * cb[iy0 * FW + ix1]
       + wy * (1.f - wx)         * cb[iy1 * FW + ix0]
       + wy * wx                 * cb[iy1 * FW + ix1];
}

__device__ __forceinline__ float wave_sum(float v) {
#pragma unroll
  for (int o = 32; o > 0; o >>= 1) v += __shfl_xor(v, o, 64);
  return v;
}

// ---------------- K1: transpose feats [C][h][w] -> [h][w][C] ----------------
__global__ __launch_bounds__(256) void k_transpose(const float* __restrict__ feat0,
                                                   const float* __restrict__ feat1,
                                                   float* __restrict__ ft0,
                                                   float* __restrict__ ft1) {
  __shared__ float tile[32][33];
  int z = blockIdx.z;
  const float* src = (z < BB) ? feat0 + (size_t)z * CCH * FHW
                              : feat1 + (size_t)(z - BB) * CCH * FHW;
  float* dst = (z < BB) ? ft0 + (size_t)z * CCH * FHW
                        : ft1 + (size_t)(z - BB) * CCH * FHW;
  int p0 = blockIdx.x * 32;   // position tile (p = y*FW + x)
  int c0 = blockIdx.y * 32;   // channel tile
  int tx = threadIdx.x & 31, ty = threadIdx.x >> 5;  // ty 0..7
#pragma unroll
  for (int jj = 0; jj < 32; jj += 8)
    tile[ty + jj][tx] = src[(size_t)(c0 + ty + jj) * FHW + p0 + tx];
  __syncthreads();
#pragma unroll
  for (int jj = 0; jj < 32; jj += 8)
    dst[(size_t)(p0 + ty + jj) * CCH + c0 + tx] = tile[tx][ty + jj];
}

// ---------------- K2: per-point prep (vf0 f32, vf0_bf, dist_bf, mask) -------
__global__ __launch_bounds__(256) void k_prep(const float* __restrict__ ft0,
                                              const float* __restrict__ ft1,
                                              const int* __restrict__ pos0,
                                              const int* __restrict__ pos1,
                                              float* __restrict__ vf0,
                                              ushort_t* __restrict__ vf0_bf,
                                              ushort_t* __restrict__ dist_bf,
                                              float* __restrict__ mask_out) {
  int wv = threadIdx.x >> 6, lane = threadIdx.x & 63;
  int n = blockIdx.x * 4 + wv;
  int b = n / NPT, r = n % NPT;

  // ---- vf0 = l2norm(bilinear(pos0[:N]/4, feat0)) ----
  {
    const float* fb = ft0 + (size_t)b * FHW * CCH;
    float py = (float)pos0[(b * MPT + r) * 2 + 0];
    float px = (float)pos0[(b * MPT + r) * 2 + 1];
    float2 v = sample2(fb, py * 0.25f, px * 0.25f, lane);
    float ss = wave_sum(v.x * v.x + v.y * v.y);
    float inv = 1.f / fmaxf(sqrtf(ss), 1e-12f);
    v.x *= inv; v.y *= inv;
    *(float2*)(vf0 + (size_t)n * CCH + 2 * lane) = v;
    ushort2 p; p.x = f2bf(v.x); p.y = f2bf(v.y);
    *(ushort2*)(vf0_bf + (size_t)n * CCH + 2 * lane) = p;
  }

  // ---- dist = l2norm(bilinear(pos1[M-N:]/4, feat1)) ----
  {
    const float* fb = ft1 + (size_t)b * FHW * CCH;
    float py = (float)pos1[(b * MPT + (MPT - NPT) + r) * 2 + 0];
    float px = (float)pos1[(b * MPT + (MPT - NPT) + r) * 2 + 1];
    float2 v = sample2(fb, py * 0.25f, px * 0.25f, lane);
    float ss = wave_sum(v.x * v.x + v.y * v.y);
    float inv = 1.f / fmaxf(sqrtf(ss), 1e-12f);
    v.x *= inv; v.y *= inv;
    ushort2 p; p.x = f2bf(v.x); p.y = f2bf(v.y);
    *(ushort2*)(dist_bf + (size_t)n * CCH + 2 * lane) = p;
  }

  // ---- mask (vp1 in-bounds) ----
  if (lane == 0) {
    int my = pos1[(b * MPT + r) * 2 + 0];
    int mx = pos1[(b * MPT + r) * 2 + 1];
    mask_out[n] = (mx >= 0 && mx < WW && my >= 0 && my < HH) ? 1.f : 0.f;
  }
}

// ---------------- K3: zero-fill gt region (contiguous float4) ---------------
__global__ __launch_bounds__(256) void k_zero(float4* __restrict__ p, int n4) {
  int i = blockIdx.x * blockDim.x + threadIdx.x;
  int stride = gridDim.x * blockDim.x;
  float4 z; z.x = 0.f; z.y = 0.f; z.z = 0.f; z.w = 0.f;
  for (; i < n4; i += stride) p[i] = z;
}

// ---------------- K4: candidates (pscore/argmax, nscores, qconf, gt col0) ---
__global__ __launch_bounds__(256) void k_cand(const float* __restrict__ ft1,
                                              const float* __restrict__ conf0,
                                              const float* __restrict__ conf1,
                                              const int* __restrict__ pos0,
                                              const int* __restrict__ pos1,
                                              const float* __restrict__ vf0,
                                              float* __restrict__ scores,
                                              float* __restrict__ gt,
                                              float* __restrict__ qconf_out) {
  int n = blockIdx.x;
  int b = n / NPT, r = n % NPT;
  int wv = threadIdx.x >> 6, lane = threadIdx.x & 63;
  const float* fb1 = ft1 + (size_t)b * FHW * CCH;
  int py = pos1[(b * MPT + r) * 2 + 0];
  int px = pos1[(b * MPT + r) * 2 + 1];
  float2 a = *(const float2*)(vf0 + (size_t)n * CCH + 2 * lane);

  __shared__ float s_best[4];
  __shared__ int   s_idx[4];

  // ---- positive candidates: wave wv takes p = wv + 4*t; batches of 4 for ILP
  float best = -1e30f; int bidx = 0;
  for (int t0 = 0; t0 < 8; t0 += 4) {
    float dots[4], sss[4];
#pragma unroll
    for (int u = 0; u < 4; ++u) {
      int p = wv + 4 * (t0 + u);
      float d = 0.f, s = 0.f;
      if (p < NPOSC) {
        float2 v = sample_cand(fb1, py + c_pos_dy[p], px + c_pos_dx[p], lane);
        d = a.x * v.x + a.y * v.y;
        s = v.x * v.x + v.y * v.y;
      }
      dots[u] = d; sss[u] = s;
    }
#pragma unroll
    for (int o = 32; o > 0; o >>= 1)
#pragma unroll
      for (int u = 0; u < 4; ++u) {
        dots[u] += __shfl_xor(dots[u], o, 64);
        sss[u]  += __shfl_xor(sss[u],  o, 64);
      }
#pragma unroll
    for (int u = 0; u < 4; ++u) {
      int p = wv + 4 * (t0 + u);
      if (p < NPOSC) {
        float sc = dots[u] / fmaxf(sqrtf(sss[u]), 1e-12f);
        if (sc > best) { best = sc; bidx = p; }   // strict > keeps first
      }
    }
  }
  if (lane == 0) { s_best[wv] = best; s_idx[wv] = bidx; }
  __syncthreads();
  if (threadIdx.x == 0) {
    float bb = s_best[0]; int bi = s_idx[0];
#pragma unroll
    for (int w2 = 1; w2 < 4; ++w2) {
      float v = s_best[w2]; int i2 = s_idx[w2];
      if (v > bb || (v == bb && i2 < bi)) { bb = v; bi = i2; }  // first-max tie
    }
    scores[(size_t)n * NCOL] = bb;
    gt[(size_t)n * NCOL] = 1.0f;   // rest of gt zeroed by k_zero
    float q0 = conf_sample(conf0 + (size_t)b * FHW,
                           (float)pos0[(b * MPT + r) * 2 + 0],
                           (float)pos0[(b * MPT + r) * 2 + 1]);
    float sy = fminf(fmaxf((float)(py + c_pos_dy[bi]), 0.f), (float)(HH - 1));
    float sx = fminf(fmaxf((float)(px + c_pos_dx[bi]), 0.f), (float)(WW - 1));
    float q1 = conf_sample(conf1 + (size_t)b * FHW, sy, sx);
    qconf_out[n] = 0.5f * (q0 + q1);
  }

  // ---- negative candidates -> scores cols 1..80; p = wv + 4*t, t=0..19 ----
  for (int t0 = 0; t0 < 20; t0 += 4) {
    float dots[4], sss[4];
#pragma unroll
    for (int u = 0; u < 4; ++u) {
      int p = wv + 4 * (t0 + u);
      float2 v = sample_cand(fb1, py + c_neg_dy[p], px + c_neg_dx[p], lane);
      dots[u] = a.x * v.x + a.y * v.y;
      sss[u]  = v.x * v.x + v.y * v.y;
    }
#pragma unroll
    for (int o = 32; o > 0; o >>= 1)
#pragma unroll
      for (int u = 0; u < 4; ++u) {
        dots[u] += __shfl_xor(dots[u], o, 64);
        sss[u]  += __shfl_xor(sss[u],  o, 64);
      }
    if (lane == 0) {
#pragma unroll
      for (int u = 0; u < 4; ++u) {
        int p = wv + 4 * (t0 + u);
        scores[(size_t)n * NCOL + 1 + p] = dots[u] / fmaxf(sqrtf(sss[u]), 1e-12f);
      }
    }
  }
}

// ---------------- K5: MFMA GEMM scores[:,81:] = vf0 @ dist.T (masked) -------
// A (vf0_bf) and B (dist_bf) are both [BNP][CCH] bf16, K-contiguous.
// Fragments loaded DIRECTLY from global (4 MB total -> lives in L2).
__global__ __launch_bounds__(256) void k_gemm(const ushort_t* __restrict__ vf0_bf,
                                              const ushort_t* __restrict__ dist_bf,
                                              const int* __restrict__ pos1,
                                              float* __restrict__ scores) {
  int i0 = blockIdx.x * 128, j0 = blockIdx.y * 128;
  int tid = threadIdx.x, lane = tid & 63, wv = tid >> 6;
  int wm = wv >> 1, wn = wv & 1;            // 2x2 wave grid (64x64 per wave)
  int mrow = lane & 15, quad = lane >> 4;

  __shared__ float s_ry[128], s_rx[128], s_rb[128];
  __shared__ float s_cy[128], s_cx[128], s_cb[128];
  if (tid < 128) {
    int i = min(i0 + tid, BNP - 1);
    int b = i / NPT, rr = i - b * NPT;
    s_ry[tid] = (float)pos1[(b * MPT + rr) * 2 + 0];
    s_rx[tid] = (float)pos1[(b * MPT + rr) * 2 + 1];
    s_rb[tid] = (float)b;
  } else {
    int t2 = tid - 128;
    int j = min(j0 + t2, BNP - 1);
    int b = j / NPT, rr = j - b * NPT;
    s_cy[t2] = (float)pos1[(b * MPT + (MPT - NPT) + rr) * 2 + 0];
    s_cx[t2] = (float)pos1[(b * MPT + (MPT - NPT) + rr) * 2 + 1];
    s_cb[t2] = (float)b;
  }
  __syncthreads();

  f32x4 acc[4][4] = {};
  const ushort_t* abase = vf0_bf  + (size_t)(i0 + wm * 64 + mrow) * CCH + quad * 8;
  const ushort_t* bbase = dist_bf + (size_t)(j0 + wn * 64 + mrow) * CCH + quad * 8;
#pragma unroll
  for (int ks = 0; ks < 4; ++ks) {          // K = 4 steps of 32
    bf16x8 af[4], bf[4];
#pragma unroll
    for (int f = 0; f < 4; ++f) {
      af[f] = *(const bf16x8*)(abase + (size_t)f * 16 * CCH + ks * 32);
      bf[f] = *(const bf16x8*)(bbase + (size_t)f * 16 * CCH + ks * 32);
    }
#pragma unroll
    for (int fm = 0; fm < 4; ++fm)
#pragma unroll
      for (int fn = 0; fn < 4; ++fn)
        acc[fm][fn] = __builtin_amdgcn_mfma_f32_16x16x32_bf16(af[fm], bf[fn],
                                                              acc[fm][fn], 0, 0, 0);
  }

  // epilogue: distance mask + coalesced dword stores (cols 81..)
  float cy[4], cx[4], cb[4]; int colg[4];
#pragma unroll
  for (int fn = 0; fn < 4; ++fn) {
    int cl = wn * 64 + fn * 16 + mrow;
    cy[fn] = s_cy[cl]; cx[fn] = s_cx[cl]; cb[fn] = s_cb[cl];
    colg[fn] = j0 + cl;
  }
#pragma unroll
  for (int fm = 0; fm < 4; ++fm) {
#pragma unroll
    for (int reg = 0; reg < 4; ++reg) {
      int rl = wm * 64 + fm * 16 + quad * 4 + reg;
      int row = i0 + rl;
      if (row >= BNP) continue;
      float ry = s_ry[rl], rx = s_rx[rl], rb = s_rb[rl];
      size_t base = (size_t)row * NCOL + 1 + NNEGC;
#pragma unroll
      for (int fn = 0; fn < 4; ++fn) {
        if (colg[fn] >= BNP) continue;
        float dy = cy[fn] - ry, dx = cx[fn] - rx;
        float d2 = dy * dy + dx * dx + ((cb[fn] != rb) ? 25.f : 0.f);
        scores[base + colg[fn]] = (d2 < 25.f) ? 0.f : acc[fm][fn][reg];
      }
    }
  }
}

// ---------------- launch ----------------
extern "C" void kernel_launch(void* const* d_in, const int* in_sizes, int n_in,
                              void* d_out, int out_size, void* d_ws, size_t ws_size,
                              hipStream_t stream) {
  (void)in_sizes; (void)n_in; (void)out_size; (void)ws_size;
  const float* feat0 = (const float*)d_in[0];
  const float* feat1 = (const float*)d_in[1];
  const float* conf0 = (const float*)d_in[2];
  const float* conf1 = (const float*)d_in[3];
  const int*   pos0  = (const int*)d_in[4];
  const int*   pos1  = (const int*)d_in[5];

  float* ws = (float*)d_ws;
  float* ft0 = ws;                                      // 4*128*128*128 f32
  float* ft1 = ft0 + (size_t)BB * CCH * FHW;
  float* vf0 = ft1 + (size_t)BB * CCH * FHW;            // 8000*128 f32
  ushort_t* vf0_bf  = (ushort_t*)(vf0 + (size_t)BNP * CCH);   // 8000*128 bf16
  ushort_t* dist_bf = vf0_bf + (size_t)BNP * CCH;             // 8000*128 bf16
  // (>=32KB slack after dist_bf exists in ws; edge-tile frag loads may over-read)

  float* out    = (float*)d_out;
  float* scores = out;                                  // [8000][8081]
  float* gt     = out + (size_t)BNP * NCOL;             // [8000][8081]
  float* maskp  = gt + (size_t)BNP * NCOL;              // [8000]
  float* qconf  = maskp + BNP;                          // [8000]

  dim3 g1(FHW / 32, CCH / 32, 2 * BB);
  k_transpose<<<g1, dim3(256), 0, stream>>>(feat0, feat1, ft0, ft1);
  k_prep<<<dim3(BNP / 4), dim3(256), 0, stream>>>(ft0, ft1, pos0, pos1,
                                                  vf0, vf0_bf, dist_bf, maskp);
  int n4 = (BNP * NCOL) / 4;                            // gt floats / 4
  k_zero<<<dim3(8192), dim3(256), 0, stream>>>((float4*)gt, n4);
  k_cand<<<dim3(BNP), dim3(256), 0, stream>>>(ft1, conf0, conf1, pos0, pos1,
                                              vf0, scores, gt, qconf);
  dim3 g5((BNP + 127) / 128, (BNP + 127) / 128);
  k_gemm<<<g5, dim3(256), 0, stream>>>(vf0_bf, dist_bf, pos1, scores);
}

// Round 3
// 752.827 us; speedup vs baseline: 1.4433x; 1.0923x over previous
//
#include <hip/hip_runtime.h>

typedef unsigned short ushort_t;
typedef __attribute__((ext_vector_type(8))) short bf16x8;
typedef __attribute__((ext_vector_type(4))) float f32x4;

// ---------------- problem constants (fixed by setup_inputs) ----------------
#define BB 4
#define HH 512
#define WW 512
#define NPT 2000          // N points kept per image
#define MPT 2500          // M points generated per image
#define CCH 128           // channels
#define FH 128            // feature map h = H/4
#define FW 128
#define FHW (FH*FW)
#define BNP (BB*NPT)      // 8000
#define NPOSC 29
#define NNEGC 80
#define NCOL (1 + NNEGC + BNP)   // 8081 columns in scores/gt

// offsets exactly in the reference enumeration order (j outer, i inner)
__constant__ int c_pos_dy[NPOSC] = {
  0,
  -2,-1,0,1,2,
  -2,-1,0,1,2,
  -3,-2,-1,0,1,2,3,
  -2,-1,0,1,2,
  -2,-1,0,1,2,
  0};
__constant__ int c_pos_dx[NPOSC] = {
  -3,
  -2,-2,-2,-2,-2,
  -1,-1,-1,-1,-1,
  0,0,0,0,0,0,0,
  1,1,1,1,1,
  2,2,2,2,2,
  3};
__constant__ int c_neg_dy[NNEGC] = {
  0,
  -3,-2,-1,0,1,2,3,
  -4,-3,-2,-1,0,1,2,3,4,
  -5,-4,-3,3,4,5,
  -6,-5,-4,4,5,6,
  -6,-5,5,6,
  -6,-5,5,6,
  -7,-6,-5,5,6,7,
  -6,-5,5,6,
  -6,-5,5,6,
  -6,-5,-4,4,5,6,
  -5,-4,-3,3,4,5,
  -4,-3,-2,-1,0,1,2,3,4,
  -3,-2,-1,0,1,2,3,
  0};
__constant__ int c_neg_dx[NNEGC] = {
  -7,
  -6,-6,-6,-6,-6,-6,-6,
  -5,-5,-5,-5,-5,-5,-5,-5,-5,
  -4,-4,-4,-4,-4,-4,
  -3,-3,-3,-3,-3,-3,
  -2,-2,-2,-2,
  -1,-1,-1,-1,
  0,0,0,0,0,0,
  1,1,1,1,
  2,2,2,2,
  3,3,3,3,3,3,
  4,4,4,4,4,4,
  5,5,5,5,5,5,5,5,5,
  6,6,6,6,6,6,6,
  7};

// ---------------- device helpers ----------------
__device__ __forceinline__ ushort_t f2bf(float f) {   // round-to-nearest-even
  unsigned u = __float_as_uint(f);
  unsigned r = (u + 0x7fffu + ((u >> 16) & 1u)) >> 16;
  return (ushort_t)r;
}

// bilinear sample of 2 channels (c = 2*lane, 2*lane+1) from channel-contiguous
// feature map fb[FH][FW][CCH]; fy/fx are feature-scale coords (already /4)
__device__ __forceinline__ float2 sample2(const float* __restrict__ fb,
                                          float fy, float fx, int lane) {
  float y = fminf(fmaxf(fy, 0.f), (float)(FH - 1));
  float x = fminf(fmaxf(fx, 0.f), (float)(FW - 1));
  float y0 = floorf(y), x0 = floorf(x);
  int iy0 = (int)y0, ix0 = (int)x0;
  int iy1 = min(iy0 + 1, FH - 1), ix1 = min(ix0 + 1, FW - 1);
  float wy = y - y0, wx = x - x0;
  float w00 = (1.f - wy) * (1.f - wx), w01 = (1.f - wy) * wx;
  float w10 = wy * (1.f - wx),         w11 = wy * wx;
  int c = 2 * lane;
  float2 a00 = *(const float2*)(fb + ((size_t)iy0 * FW + ix0) * CCH + c);
  float2 a01 = *(const float2*)(fb + ((size_t)iy0 * FW + ix1) * CCH + c);
  float2 a10 = *(const float2*)(fb + ((size_t)iy1 * FW + ix0) * CCH + c);
  float2 a11 = *(const float2*)(fb + ((size_t)iy1 * FW + ix1) * CCH + c);
  float2 r;
  r.x = w00 * a00.x + w01 * a01.x + w10 * a10.x + w11 * a11.x;
  r.y = w00 * a00.y + w01 * a01.y + w10 * a10.y + w11 * a11.y;
  return r;
}

// single-channel bilinear on conf map cb[FH][FW]; py/px are IMAGE-scale coords
__device__ __forceinline__ float conf_sample(const float* __restrict__ cb,
                                             float py, float px) {
  float y = fminf(fmaxf(py * 0.25f, 0.f), (float)(FH - 1));
  float x = fminf(fmaxf(px * 0.25f, 0.f), (float)(FW - 1));
  float y0 = floorf(y), x0 = floorf(x);
  int iy0 = (int)y0, ix0 = (int)x0;
  int iy1 = min(iy0 + 1, FH - 1), ix1 = min(ix0 + 1, FW - 1);
  float wy = y - y0, wx = x - x0;
  return (1.f - wy) * (1.f - wx) * cb[iy0 * FW + ix0]
       + (1.f - wy) * wx         * cb[iy0 * FW + ix1]
       + wy * (1.f - wx)         * cb[iy1 * FW + ix0]
       + wy * wx                 * cb[iy1 * FW + ix1];
}

__device__ __forceinline__ float wave_sum(float v) {
#pragma unroll
  for (int o = 32; o > 0; o >>= 1) v += __shfl_xor(v, o, 64);
  return v;
}

// per-lane partial (dot, ss) of one candidate: this lane covers channels
// sub*8 .. sub*8+7. (dy,dx) integer offset at IMAGE scale.
__device__ __forceinline__ void cand_partial(const float* __restrict__ fb,
                                             int py, int px, int dy, int dx,
                                             int sub, const float* __restrict__ a8,
                                             float& dot, float& ss) {
  float cy = fminf(fmaxf((float)(py + dy), 0.f), (float)(HH - 1)) * 0.25f;
  float cx = fminf(fmaxf((float)(px + dx), 0.f), (float)(WW - 1)) * 0.25f;
  float y = fminf(cy, (float)(FH - 1));
  float x = fminf(cx, (float)(FW - 1));
  float y0 = floorf(y), x0 = floorf(x);
  int iy0 = (int)y0, ix0 = (int)x0;
  int iy1 = min(iy0 + 1, FH - 1), ix1 = min(ix0 + 1, FW - 1);
  float wy = y - y0, wx = x - x0;
  float w00 = (1.f - wy) * (1.f - wx), w01 = (1.f - wy) * wx;
  float w10 = wy * (1.f - wx),         w11 = wy * wx;
  const float* p00 = fb + ((size_t)iy0 * FW + ix0) * CCH + sub * 8;
  const float* p01 = fb + ((size_t)iy0 * FW + ix1) * CCH + sub * 8;
  const float* p10 = fb + ((size_t)iy1 * FW + ix0) * CCH + sub * 8;
  const float* p11 = fb + ((size_t)iy1 * FW + ix1) * CCH + sub * 8;
  float c00[8], c01[8], c10[8], c11[8];
  *(float4*)&c00[0] = *(const float4*)p00; *(float4*)&c00[4] = *(const float4*)(p00 + 4);
  *(float4*)&c01[0] = *(const float4*)p01; *(float4*)&c01[4] = *(const float4*)(p01 + 4);
  *(float4*)&c10[0] = *(const float4*)p10; *(float4*)&c10[4] = *(const float4*)(p10 + 4);
  *(float4*)&c11[0] = *(const float4*)p11; *(float4*)&c11[4] = *(const float4*)(p11 + 4);
  float d = 0.f, s = 0.f;
#pragma unroll
  for (int ch = 0; ch < 8; ++ch) {
    float v = w00 * c00[ch] + w01 * c01[ch] + w10 * c10[ch] + w11 * c11[ch];
    d += a8[ch] * v;
    s += v * v;
  }
  dot = d; ss = s;
}

__device__ __forceinline__ void better(float& best, int& bidx, float ob, int oi) {
  if (ob > best || (ob == best && oi < bidx)) { best = ob; bidx = oi; }
}

// ---------------- K1: transpose feats [C][h][w] -> [h][w][C] ----------------
__global__ __launch_bounds__(256) void k_transpose(const float* __restrict__ feat0,
                                                   const float* __restrict__ feat1,
                                                   float* __restrict__ ft0,
                                                   float* __restrict__ ft1) {
  __shared__ float tile[32][33];
  int z = blockIdx.z;
  const float* src = (z < BB) ? feat0 + (size_t)z * CCH * FHW
                              : feat1 + (size_t)(z - BB) * CCH * FHW;
  float* dst = (z < BB) ? ft0 + (size_t)z * CCH * FHW
                        : ft1 + (size_t)(z - BB) * CCH * FHW;
  int p0 = blockIdx.x * 32;   // position tile (p = y*FW + x)
  int c0 = blockIdx.y * 32;   // channel tile
  int tx = threadIdx.x & 31, ty = threadIdx.x >> 5;  // ty 0..7
#pragma unroll
  for (int jj = 0; jj < 32; jj += 8)
    tile[ty + jj][tx] = src[(size_t)(c0 + ty + jj) * FHW + p0 + tx];
  __syncthreads();
#pragma unroll
  for (int jj = 0; jj < 32; jj += 8)
    dst[(size_t)(p0 + ty + jj) * CCH + c0 + tx] = tile[tx][ty + jj];
}

// ---------------- K2: per-point prep (vf0 f32, vf0_bf, dist_bf, mask) -------
__global__ __launch_bounds__(256) void k_prep(const float* __restrict__ ft0,
                                              const float* __restrict__ ft1,
                                              const int* __restrict__ pos0,
                                              const int* __restrict__ pos1,
                                              float* __restrict__ vf0,
                                              ushort_t* __restrict__ vf0_bf,
                                              ushort_t* __restrict__ dist_bf,
                                              float* __restrict__ mask_out) {
  int wv = threadIdx.x >> 6, lane = threadIdx.x & 63;
  int n = blockIdx.x * 4 + wv;
  int b = n / NPT, r = n % NPT;

  // ---- vf0 = l2norm(bilinear(pos0[:N]/4, feat0)) ----
  {
    const float* fb = ft0 + (size_t)b * FHW * CCH;
    float py = (float)pos0[(b * MPT + r) * 2 + 0];
    float px = (float)pos0[(b * MPT + r) * 2 + 1];
    float2 v = sample2(fb, py * 0.25f, px * 0.25f, lane);
    float ss = wave_sum(v.x * v.x + v.y * v.y);
    float inv = 1.f / fmaxf(sqrtf(ss), 1e-12f);
    v.x *= inv; v.y *= inv;
    *(float2*)(vf0 + (size_t)n * CCH + 2 * lane) = v;
    ushort2 p; p.x = f2bf(v.x); p.y = f2bf(v.y);
    *(ushort2*)(vf0_bf + (size_t)n * CCH + 2 * lane) = p;
  }

  // ---- dist = l2norm(bilinear(pos1[M-N:]/4, feat1)) ----
  {
    const float* fb = ft1 + (size_t)b * FHW * CCH;
    float py = (float)pos1[(b * MPT + (MPT - NPT) + r) * 2 + 0];
    float px = (float)pos1[(b * MPT + (MPT - NPT) + r) * 2 + 1];
    float2 v = sample2(fb, py * 0.25f, px * 0.25f, lane);
    float ss = wave_sum(v.x * v.x + v.y * v.y);
    float inv = 1.f / fmaxf(sqrtf(ss), 1e-12f);
    v.x *= inv; v.y *= inv;
    ushort2 p; p.x = f2bf(v.x); p.y = f2bf(v.y);
    *(ushort2*)(dist_bf + (size_t)n * CCH + 2 * lane) = p;
  }

  // ---- mask (vp1 in-bounds) ----
  if (lane == 0) {
    int my = pos1[(b * MPT + r) * 2 + 0];
    int mx = pos1[(b * MPT + r) * 2 + 1];
    mask_out[n] = (mx >= 0 && mx < WW && my >= 0 && my < HH) ? 1.f : 0.f;
  }
}

// ---------------- K3: zero-fill gt region (contiguous float4) ---------------
__global__ __launch_bounds__(256) void k_zero(float4* __restrict__ p, int n4) {
  int i = blockIdx.x * blockDim.x + threadIdx.x;
  int stride = gridDim.x * blockDim.x;
  float4 z; z.x = 0.f; z.y = 0.f; z.z = 0.f; z.w = 0.f;
  for (; i < n4; i += stride) p[i] = z;
}

// ---------------- K4: candidates, 16-lane-group scoring ---------------------
// block = 256 threads = 4 waves; one point per block.
// Each 16-lane group scores one candidate (8 channels per lane); reduction is
// 4 xor-shuffle steps within the group; a wave scores 4 candidates at once.
__global__ __launch_bounds__(256) void k_cand(const float* __restrict__ ft1,
                                              const float* __restrict__ conf0,
                                              const float* __restrict__ conf1,
                                              const int* __restrict__ pos0,
                                              const int* __restrict__ pos1,
                                              const float* __restrict__ vf0,
                                              float* __restrict__ scores,
                                              float* __restrict__ gt,
                                              float* __restrict__ qconf_out) {
  int n = blockIdx.x;
  int b = n / NPT, r = n % NPT;
  int tid = threadIdx.x;
  int lane = tid & 63, wv = tid >> 6;
  int g = lane >> 4;            // candidate slot within wave (0..3)
  int sub = lane & 15;          // channel group; ch = sub*8 .. sub*8+7
  const float* fb1 = ft1 + (size_t)b * FHW * CCH;
  int py = pos1[(b * MPT + r) * 2 + 0];
  int px = pos1[(b * MPT + r) * 2 + 1];

  float a8[8];
  *(float4*)&a8[0] = *(const float4*)(vf0 + (size_t)n * CCH + sub * 8);
  *(float4*)&a8[4] = *(const float4*)(vf0 + (size_t)n * CCH + sub * 8 + 4);

  __shared__ float s_best[4];
  __shared__ int   s_idx[4];

  // ---- positive candidates: p = it*16 + wv*4 + g, it = 0..1 (p < 29) ------
  float best = -1e30f; int bidx = 0x7fffffff;
#pragma unroll
  for (int it = 0; it < 2; ++it) {
    int p = it * 16 + wv * 4 + g;
    int pc = min(p, NPOSC - 1);
    float dot, ss;
    cand_partial(fb1, py, px, c_pos_dy[pc], c_pos_dx[pc], sub, a8, dot, ss);
#pragma unroll
    for (int o = 1; o < 16; o <<= 1) {
      dot += __shfl_xor(dot, o, 64);
      ss  += __shfl_xor(ss,  o, 64);
    }
    float sc = dot / fmaxf(sqrtf(ss), 1e-12f);
    if (p < NPOSC && sc > best) { best = sc; bidx = p; }  // strict > = first max
  }
  // combine the 4 groups of this wave (tie-break: smaller index)
  {
    float ob = __shfl_xor(best, 16, 64); int oi = __shfl_xor(bidx, 16, 64);
    better(best, bidx, ob, oi);
    ob = __shfl_xor(best, 32, 64); oi = __shfl_xor(bidx, 32, 64);
    better(best, bidx, ob, oi);
  }
  if (lane == 0) { s_best[wv] = best; s_idx[wv] = bidx; }
  __syncthreads();
  if (tid == 0) {
    float bb = s_best[0]; int bi = s_idx[0];
#pragma unroll
    for (int w2 = 1; w2 < 4; ++w2) better(bb, bi, s_best[w2], s_idx[w2]);
    scores[(size_t)n * NCOL] = bb;
    gt[(size_t)n * NCOL] = 1.0f;   // rest of gt zeroed by k_zero
    float q0 = conf_sample(conf0 + (size_t)b * FHW,
                           (float)pos0[(b * MPT + r) * 2 + 0],
                           (float)pos0[(b * MPT + r) * 2 + 1]);
    float sy = fminf(fmaxf((float)(py + c_pos_dy[bi]), 0.f), (float)(HH - 1));
    float sx = fminf(fmaxf((float)(px + c_pos_dx[bi]), 0.f), (float)(WW - 1));
    float q1 = conf_sample(conf1 + (size_t)b * FHW, sy, sx);
    qconf_out[n] = 0.5f * (q0 + q1);
  }

  // ---- negative candidates: p = it*16 + wv*4 + g, it = 0..4 (exactly 80) --
#pragma unroll
  for (int it = 0; it < 5; ++it) {
    int p = it * 16 + wv * 4 + g;
    float dot, ss;
    cand_partial(fb1, py, px, c_neg_dy[p], c_neg_dx[p], sub, a8, dot, ss);
#pragma unroll
    for (int o = 1; o < 16; o <<= 1) {
      dot += __shfl_xor(dot, o, 64);
      ss  += __shfl_xor(ss,  o, 64);
    }
    if (sub == 0)
      scores[(size_t)n * NCOL + 1 + p] = dot / fmaxf(sqrtf(ss), 1e-12f);
  }
}

// ---------------- K5: MFMA GEMM scores[:,81:] = vf0 @ dist.T (masked) -------
// A (vf0_bf) and B (dist_bf) are both [BNP][CCH] bf16, K-contiguous.
// Fragments loaded DIRECTLY from global (4 MB total -> lives in L2).
__global__ __launch_bounds__(256) void k_gemm(const ushort_t* __restrict__ vf0_bf,
                                              const ushort_t* __restrict__ dist_bf,
                                              const int* __restrict__ pos1,
                                              float* __restrict__ scores) {
  int i0 = blockIdx.x * 128, j0 = blockIdx.y * 128;
  int tid = threadIdx.x, lane = tid & 63, wv = tid >> 6;
  int wm = wv >> 1, wn = wv & 1;            // 2x2 wave grid (64x64 per wave)
  int mrow = lane & 15, quad = lane >> 4;

  __shared__ float s_ry[128], s_rx[128], s_rb[128];
  __shared__ float s_cy[128], s_cx[128], s_cb[128];
  if (tid < 128) {
    int i = min(i0 + tid, BNP - 1);
    int b = i / NPT, rr = i - b * NPT;
    s_ry[tid] = (float)pos1[(b * MPT + rr) * 2 + 0];
    s_rx[tid] = (float)pos1[(b * MPT + rr) * 2 + 1];
    s_rb[tid] = (float)b;
  } else {
    int t2 = tid - 128;
    int j = min(j0 + t2, BNP - 1);
    int b = j / NPT, rr = j - b * NPT;
    s_cy[t2] = (float)pos1[(b * MPT + (MPT - NPT) + rr) * 2 + 0];
    s_cx[t2] = (float)pos1[(b * MPT + (MPT - NPT) + rr) * 2 + 1];
    s_cb[t2] = (float)b;
  }
  __syncthreads();

  f32x4 acc[4][4] = {};
  const ushort_t* abase = vf0_bf  + (size_t)(i0 + wm * 64 + mrow) * CCH + quad * 8;
  const ushort_t* bbase = dist_bf + (size_t)(j0 + wn * 64 + mrow) * CCH + quad * 8;
#pragma unroll
  for (int ks = 0; ks < 4; ++ks) {          // K = 4 steps of 32
    bf16x8 af[4], bf[4];
#pragma unroll
    for (int f = 0; f < 4; ++f) {
      af[f] = *(const bf16x8*)(abase + (size_t)f * 16 * CCH + ks * 32);
      bf[f] = *(const bf16x8*)(bbase + (size_t)f * 16 * CCH + ks * 32);
    }
#pragma unroll
    for (int fm = 0; fm < 4; ++fm)
#pragma unroll
      for (int fn = 0; fn < 4; ++fn)
        acc[fm][fn] = __builtin_amdgcn_mfma_f32_16x16x32_bf16(af[fm], bf[fn],
                                                              acc[fm][fn], 0, 0, 0);
  }

  // epilogue: distance mask + coalesced dword stores (cols 81..)
  float cy[4], cx[4], cb[4]; int colg[4];
#pragma unroll
  for (int fn = 0; fn < 4; ++fn) {
    int cl = wn * 64 + fn * 16 + mrow;
    cy[fn] = s_cy[cl]; cx[fn] = s_cx[cl]; cb[fn] = s_cb[cl];
    colg[fn] = j0 + cl;
  }
#pragma unroll
  for (int fm = 0; fm < 4; ++fm) {
#pragma unroll
    for (int reg = 0; reg < 4; ++reg) {
      int rl = wm * 64 + fm * 16 + quad * 4 + reg;
      int row = i0 + rl;
      if (row >= BNP) continue;
      float ry = s_ry[rl], rx = s_rx[rl], rb = s_rb[rl];
      size_t base = (size_t)row * NCOL + 1 + NNEGC;
#pragma unroll
      for (int fn = 0; fn < 4; ++fn) {
        if (colg[fn] >= BNP) continue;
        float dy = cy[fn] - ry, dx = cx[fn] - rx;
        float d2 = dy * dy + dx * dx + ((cb[fn] != rb) ? 25.f : 0.f);
        scores[base + colg[fn]] = (d2 < 25.f) ? 0.f : acc[fm][fn][reg];
      }
    }
  }
}

// ---------------- launch ----------------
extern "C" void kernel_launch(void* const* d_in, const int* in_sizes, int n_in,
                              void* d_out, int out_size, void* d_ws, size_t ws_size,
                              hipStream_t stream) {
  (void)in_sizes; (void)n_in; (void)out_size; (void)ws_size;
  const float* feat0 = (const float*)d_in[0];
  const float* feat1 = (const float*)d_in[1];
  const float* conf0 = (const float*)d_in[2];
  const float* conf1 = (const float*)d_in[3];
  const int*   pos0  = (const int*)d_in[4];
  const int*   pos1  = (const int*)d_in[5];

  float* ws = (float*)d_ws;
  float* ft0 = ws;                                      // 4*128*128*128 f32
  float* ft1 = ft0 + (size_t)BB * CCH * FHW;
  float* vf0 = ft1 + (size_t)BB * CCH * FHW;            // 8000*128 f32
  ushort_t* vf0_bf  = (ushort_t*)(vf0 + (size_t)BNP * CCH);   // 8000*128 bf16
  ushort_t* dist_bf = vf0_bf + (size_t)BNP * CCH;             // 8000*128 bf16

  float* out    = (float*)d_out;
  float* scores = out;                                  // [8000][8081]
  float* gt     = out + (size_t)BNP * NCOL;             // [8000][8081]
  float* maskp  = gt + (size_t)BNP * NCOL;              // [8000]
  float* qconf  = maskp + BNP;                          // [8000]

  dim3 g1(FHW / 32, CCH / 32, 2 * BB);
  k_transpose<<<g1, dim3(256), 0, stream>>>(feat0, feat1, ft0, ft1);
  k_prep<<<dim3(BNP / 4), dim3(256), 0, stream>>>(ft0, ft1, pos0, pos1,
                                                  vf0, vf0_bf, dist_bf, maskp);
  int n4 = (BNP * NCOL) / 4;                            // gt floats / 4
  k_zero<<<dim3(8192), dim3(256), 0, stream>>>((float4*)gt, n4);
  k_cand<<<dim3(BNP), dim3(256), 0, stream>>>(ft1, conf0, conf1, pos0, pos1,
                                              vf0, scores, gt, qconf);
  dim3 g5((BNP + 127) / 128, (BNP + 127) / 128);
  k_gemm<<<g5, dim3(256), 0, stream>>>(vf0_bf, dist_bf, pos1, scores);
}